// Round 5
// baseline (634.400 us; speedup 1.0000x reference)
//
#include <hip/hip_runtime.h>
#include <hip/hip_bf16.h>

typedef unsigned short u16;
typedef unsigned int u32;
typedef __attribute__((ext_vector_type(8))) short bf16x8;
typedef __attribute__((ext_vector_type(4))) float f32x4;

#define NG 100000
#define NV 200000
#define NE 500000
#define HD 128

__device__ __forceinline__ float bflo(u32 w) { return __uint_as_float(w << 16); }
__device__ __forceinline__ float bfhi(u32 w) { return __uint_as_float(w & 0xffff0000u); }
__device__ __forceinline__ u16 f2bf(float f) {
    __hip_bfloat16 h = __float2bfloat16(f);
    u16 u; __builtin_memcpy(&u, &h, 2); return u;
}

// ---- histogram: deg[dst[e]] += 1 ----
__global__ __launch_bounds__(256) void hist_kernel(const int* __restrict__ dst,
                                                   int* __restrict__ deg, int E) {
    int e = blockIdx.x * 256 + threadIdx.x;
    if (e < E) atomicAdd(&deg[dst[e]], 1);
}

// ---- scan stage 1: per-block (2048 elems) exclusive scan + block sums ----
__global__ __launch_bounds__(256) void scan1_kernel(const int* __restrict__ deg,
                                                    int* __restrict__ excl,
                                                    int* __restrict__ bsum, int N) {
    __shared__ int lds[256];
    int tid = threadIdx.x;
    int base = blockIdx.x * 2048 + tid * 8;
    int v[8]; int s = 0;
#pragma unroll
    for (int i = 0; i < 8; ++i) { v[i] = (base + i < N) ? deg[base + i] : 0; s += v[i]; }
    lds[tid] = s;
    __syncthreads();
    for (int off = 1; off < 256; off <<= 1) {
        int x = (tid >= off) ? lds[tid - off] : 0;
        __syncthreads();
        lds[tid] += x;
        __syncthreads();
    }
    int run = lds[tid] - s;
#pragma unroll
    for (int i = 0; i < 8; ++i) {
        if (base + i < N) excl[base + i] = run;
        run += v[i];
    }
    if (tid == 255) bsum[blockIdx.x] = lds[255];
}

// ---- scan stage 2: exclusive scan of block sums ----
__global__ void scan2_kernel(int* __restrict__ bsum, int nb) {
    if (threadIdx.x == 0 && blockIdx.x == 0) {
        int run = 0;
        for (int i = 0; i < nb; ++i) { int t = bsum[i]; bsum[i] = run; run += t; }
    }
}

// ---- scan stage 3: add block offsets; emit row_start + cursor copy ----
__global__ __launch_bounds__(256) void scan3_kernel(int* __restrict__ rs,
                                                    int* __restrict__ cur,
                                                    const int* __restrict__ bsum,
                                                    int N, int E) {
    int i = blockIdx.x * 256 + threadIdx.x;
    if (i < N) {
        int v = rs[i] + bsum[i >> 11];
        rs[i] = v;
        cur[i] = v;
    }
    if (i == 0) rs[N] = E;
}

// ---- edge scatter: esrc[cur[dst[e]]++] = src[e] ----
__global__ __launch_bounds__(256) void escatter_kernel(const int* __restrict__ src,
                                                       const int* __restrict__ dst,
                                                       int* __restrict__ cur,
                                                       int* __restrict__ esrc, int E) {
    int e = blockIdx.x * 256 + threadIdx.x;
    if (e < E) {
        int p = atomicAdd(&cur[dst[e]], 1);
        esrc[p] = src[e];
    }
}

// ---- gather-sum aggregate: aggb[row] = bf16( mean_{e in CSR[row]} X[esrc[e]] ) ----
template <int XBF16>
__global__ __launch_bounds__(256) void aggregate_kernel(const void* __restrict__ Xv,
                                                        const int* __restrict__ rs,
                                                        const int* __restrict__ esrc,
                                                        u16* __restrict__ aggb, int N) {
    u32 t = blockIdx.x * 256 + threadIdx.x;
    int row = t >> 4, c = t & 15;
    if (row >= N) return;
    int e0 = rs[row], e1 = rs[row + 1];
    float s[8] = {0.f, 0.f, 0.f, 0.f, 0.f, 0.f, 0.f, 0.f};
    if (XBF16) {
        const u16* X = (const u16*)Xv;
        for (int e = e0; e < e1; ++e) {
            const u16* p = X + (size_t)esrc[e] * HD + c * 8;
            uint4 u = *(const uint4*)p;
            u32 w[4] = {u.x, u.y, u.z, u.w};
#pragma unroll
            for (int i = 0; i < 4; ++i) { s[2 * i] += bflo(w[i]); s[2 * i + 1] += bfhi(w[i]); }
        }
    } else {
        const float* X = (const float*)Xv;
        for (int e = e0; e < e1; ++e) {
            const float* p = X + (size_t)esrc[e] * HD + c * 8;
            float4 a = *(const float4*)p;
            float4 b = *(const float4*)(p + 4);
            s[0] += a.x; s[1] += a.y; s[2] += a.z; s[3] += a.w;
            s[4] += b.x; s[5] += b.y; s[6] += b.z; s[7] += b.w;
        }
    }
    float rcv = 1.f / fmaxf((float)(e1 - e0), 1.f);
    uint4 pk;
    pk.x = (u32)f2bf(s[0] * rcv) | ((u32)f2bf(s[1] * rcv) << 16);
    pk.y = (u32)f2bf(s[2] * rcv) | ((u32)f2bf(s[3] * rcv) << 16);
    pk.z = (u32)f2bf(s[4] * rcv) | ((u32)f2bf(s[5] * rcv) << 16);
    pk.w = (u32)f2bf(s[6] * rcv) | ((u32)f2bf(s[7] * rcv) << 16);
    *(uint4*)(aggb + (size_t)row * HD + c * 8) = pk;
}

// ---- MFMA fused SAGE linear: out = act( Agg @ Wl^T + X @ Wr^T + b ) ----
// 16x16x32 bf16 MFMA. Block = 256 thr = 4 waves; wave owns 32 rows (2 row-tiles);
// block covers 128 rows. W staged per-phase into a single 32 KB fragment-linear
// LDS buffer (conflict-free by construction). acc = 64 regs/lane -> target
// 4 waves/SIMD via __launch_bounds__(256,4).
// Fragment map (m89-verified): A row=lane&15, k=8*(lane>>4)+j; B col=lane&15;
// D col=lane&15, row=4*(lane>>4)+reg.
template <int HAS_AGG, int XF32, int RELU>
__global__ __launch_bounds__(256, 4) void mfma_gemm_kernel(
    const u16* __restrict__ Agg,
    const void* __restrict__ Xv,
    const float* __restrict__ Wl, const float* __restrict__ Wr,
    const float* __restrict__ bias,
    float* __restrict__ outf, u16* __restrict__ outb, int N)
{
    constexpr int NPH = HAS_AGG ? 2 : 1;
    __shared__ u16 wlds[32][64][8];  // [frag=kt*8+ct][lane][8] : 32 KB
    const int tid = threadIdx.x;
    const int lane = tid & 63;
    const int wid = tid >> 6;
    const int m0 = blockIdx.x * 128 + wid * 32;
    const int lr = lane & 15, lg = lane >> 4;

    f32x4 acc[2][8];
#pragma unroll
    for (int rt = 0; rt < 2; ++rt)
#pragma unroll
        for (int ct = 0; ct < 8; ++ct) acc[rt][ct] = (f32x4){0.f, 0.f, 0.f, 0.f};

#pragma unroll
    for (int ph = 0; ph < NPH; ++ph) {
        const bool isAgg = (NPH == 2 && ph == 0);
        if (ph) __syncthreads();  // all waves done reading previous W
        {   // stage this phase's W: f32 -> bf16, fragment-linear
            const float* W = isAgg ? Wl : Wr;
#pragma unroll
            for (int it = 0; it < 8; ++it) {
                int slot = it * 256 + tid;       // 0..2047
                int f = slot >> 6, l = slot & 63;
                int kt = f >> 3, ct = f & 7;
                int row = ct * 16 + (l & 15);
                int kof = kt * 32 + (l >> 4) * 8;
                const float* wp = W + (size_t)row * HD + kof;
                float4 x = *(const float4*)wp;
                float4 y = *(const float4*)(wp + 4);
                uint4 pk;
                pk.x = (u32)f2bf(x.x) | ((u32)f2bf(x.y) << 16);
                pk.y = (u32)f2bf(x.z) | ((u32)f2bf(x.w) << 16);
                pk.z = (u32)f2bf(y.x) | ((u32)f2bf(y.y) << 16);
                pk.w = (u32)f2bf(y.z) | ((u32)f2bf(y.w) << 16);
                *(uint4*)&wlds[f][l][0] = pk;
            }
        }
        __syncthreads();
#pragma unroll
        for (int kt = 0; kt < 4; ++kt) {
            bf16x8 a[2];
            if (isAgg || !XF32) {
                const u16* A = isAgg ? Agg : (const u16*)Xv;
#pragma unroll
                for (int rt = 0; rt < 2; ++rt) {
                    int row = m0 + rt * 16 + lr; if (row > N - 1) row = N - 1;
                    a[rt] = *(const bf16x8*)(A + (size_t)row * HD + kt * 32 + lg * 8);
                }
            } else {
                const float* A = (const float*)Xv;
#pragma unroll
                for (int rt = 0; rt < 2; ++rt) {
                    int row = m0 + rt * 16 + lr; if (row > N - 1) row = N - 1;
                    const float* p = A + (size_t)row * HD + kt * 32 + lg * 8;
                    float4 x = *(const float4*)p;
                    float4 y = *(const float4*)(p + 4);
                    union { u16 s[8]; bf16x8 v; } u;
                    u.s[0] = f2bf(x.x); u.s[1] = f2bf(x.y); u.s[2] = f2bf(x.z); u.s[3] = f2bf(x.w);
                    u.s[4] = f2bf(y.x); u.s[5] = f2bf(y.y); u.s[6] = f2bf(y.z); u.s[7] = f2bf(y.w);
                    a[rt] = u.v;
                }
            }
#pragma unroll
            for (int ct = 0; ct < 8; ++ct) {
                bf16x8 wfrag = *(const bf16x8*)&wlds[kt * 8 + ct][lane][0];
#pragma unroll
                for (int rt = 0; rt < 2; ++rt)
                    acc[rt][ct] = __builtin_amdgcn_mfma_f32_16x16x32_bf16(
                        a[rt], wfrag, acc[rt][ct], 0, 0, 0);
            }
        }
    }

    // epilogue: + bias, relu, store (D: col=lane&15, row=4*(lane>>4)+reg)
#pragma unroll
    for (int ct = 0; ct < 8; ++ct) {
        int col = ct * 16 + lr;
        float bcol = bias[col];
#pragma unroll
        for (int rt = 0; rt < 2; ++rt) {
            int rb = m0 + rt * 16 + lg * 4;
#pragma unroll
            for (int r = 0; r < 4; ++r) {
                int row = rb + r;
                if (row >= N) continue;
                float v = acc[rt][ct][r] + bcol;
                if (RELU) v = fmaxf(v, 0.f);
                if (outf) outf[(size_t)row * HD + col] = v;
                if (outb) outb[(size_t)row * HD + col] = f2bf(v);
            }
        }
    }
}

// ---- adversarial head stage 2: adv = hdn @ A2^T + b2  (128 -> 8), hdn bf16 ----
__global__ __launch_bounds__(256) void head2_kernel(const u16* __restrict__ hdn,
                                                    const float* __restrict__ A2,
                                                    const float* __restrict__ b2,
                                                    float* __restrict__ adv, int N)
{
    int tid = threadIdx.x;
    int r = blockIdx.x * 32 + (tid >> 3);
    int o = tid & 7;
    if (r >= N) return;
    const u16* hp = hdn + (size_t)r * HD;
    const float* ap = A2 + (size_t)o * HD;
    float acc = 0.f;
#pragma unroll 4
    for (int k = 0; k < HD; k += 8) {
        uint4 u = *(const uint4*)(hp + k);
        float4 a0 = *(const float4*)(ap + k);
        float4 a1 = *(const float4*)(ap + k + 4);
        u32 w[4] = {u.x, u.y, u.z, u.w};
        acc = fmaf(bflo(w[0]), a0.x, acc); acc = fmaf(bfhi(w[0]), a0.y, acc);
        acc = fmaf(bflo(w[1]), a0.z, acc); acc = fmaf(bfhi(w[1]), a0.w, acc);
        acc = fmaf(bflo(w[2]), a1.x, acc); acc = fmaf(bfhi(w[2]), a1.y, acc);
        acc = fmaf(bflo(w[3]), a1.z, acc); acc = fmaf(bfhi(w[3]), a1.w, acc);
    }
    adv[(size_t)r * 8 + o] = acc + b2[o];
}

extern "C" void kernel_launch(void* const* d_in, const int* in_sizes, int n_in,
                              void* d_out, int out_size, void* d_ws, size_t ws_size,
                              hipStream_t stream)
{
    const float* emb_gene = (const float*)d_in[0];
    const float* emb_var  = (const float*)d_in[1];
    const float* Wl1_gv = (const float*)d_in[2];
    const float* bl1_gv = (const float*)d_in[3];
    const float* Wr1_gv = (const float*)d_in[4];
    const float* Wl1_vg = (const float*)d_in[5];
    const float* bl1_vg = (const float*)d_in[6];
    const float* Wr1_vg = (const float*)d_in[7];
    const float* Wl2_gv = (const float*)d_in[8];
    const float* bl2_gv = (const float*)d_in[9];
    const float* Wr2_gv = (const float*)d_in[10];
    const float* Wl2_vg = (const float*)d_in[11];
    const float* bl2_vg = (const float*)d_in[12];
    const float* Wr2_vg = (const float*)d_in[13];
    const float* A1 = (const float*)d_in[14];
    const float* b1 = (const float*)d_in[15];
    const float* A2 = (const float*)d_in[16];
    const float* b2 = (const float*)d_in[17];
    const int* src_gv = (const int*)d_in[18];
    const int* dst_gv = (const int*)d_in[19];
    const int* src_vg = (const int*)d_in[20];
    const int* dst_vg = (const int*)d_in[21];

    // ws layout (bytes) — total ~213.1 MB < 231.6 MB proven:
    char* ws = (char*)d_ws;
    u16* agg_var  = (u16*)(ws);                 // bf16 [NV][128]  51.2 MB
    u16* agg_gene = (u16*)(ws + 51200000);      // bf16 [NG][128]  25.6 MB
    u16* z_var    = (u16*)(ws + 76800000);      // bf16 [NV][128]  51.2 MB
    u16* z_gene   = (u16*)(ws + 128000000);     // bf16 [NG][128]  25.6 MB
    u16* g2b      = (u16*)(ws + 153600000);     // bf16 [NG][128]  25.6 MB (gene2 for head)
    u16* hdn_b    = (u16*)(ws + 179200000);     // bf16 [NG][128]  25.6 MB
    int* rs_var   = (int*)(ws + 204800000);     // [NV+1]
    int* rs_gene  = (int*)(ws + 205700000);     // [NG+1]
    int* esrc_gv  = (int*)(ws + 206200000);     // [E]
    int* esrc_vg  = (int*)(ws + 208200000);     // [E]
    int* deg_var  = (int*)(ws + 210200000);     // [NV] transient
    int* deg_gene = (int*)(ws + 211000000);     // [NG] transient
    int* cur_var  = (int*)(ws + 211400000);     // [NV] transient
    int* cur_gene = (int*)(ws + 212200000);     // [NG] transient
    int* bs_var   = (int*)(ws + 213000000);     // [98]
    int* bs_gene  = (int*)(ws + 213100000);     // [49]

    float* out       = (float*)d_out;
    float* out_gene2 = out;                          // [NG][128]
    float* out_var2  = out + (size_t)NG * HD;        // [NV][128]
    float* out_adv   = out + (size_t)(NG + NV) * HD; // [NG][8]

    const int NB_V = (NV + 2047) / 2048;  // 98
    const int NB_G = (NG + 2047) / 2048;  // 49
    const int EB = (NE + 255) / 256;
    const int GB_V = (NV + 127) / 128;    // 1563
    const int GB_G = (NG + 127) / 128;    // 782

    // ---- CSR build (shared by both layers) ----
    hipMemsetAsync(ws + 210200000, 0, 1200000, stream);  // deg_var + deg_gene
    hist_kernel<<<EB, 256, 0, stream>>>(dst_gv, deg_var, NE);
    hist_kernel<<<EB, 256, 0, stream>>>(dst_vg, deg_gene, NE);
    scan1_kernel<<<NB_V, 256, 0, stream>>>(deg_var, rs_var, bs_var, NV);
    scan1_kernel<<<NB_G, 256, 0, stream>>>(deg_gene, rs_gene, bs_gene, NG);
    scan2_kernel<<<1, 64, 0, stream>>>(bs_var, NB_V);
    scan2_kernel<<<1, 64, 0, stream>>>(bs_gene, NB_G);
    scan3_kernel<<<(NV + 255) / 256, 256, 0, stream>>>(rs_var, cur_var, bs_var, NV, NE);
    scan3_kernel<<<(NG + 255) / 256, 256, 0, stream>>>(rs_gene, cur_gene, bs_gene, NG, NE);
    escatter_kernel<<<EB, 256, 0, stream>>>(src_gv, dst_gv, cur_var, esrc_gv, NE);
    escatter_kernel<<<EB, 256, 0, stream>>>(src_vg, dst_vg, cur_gene, esrc_vg, NE);

    // ---- layer 1: f32 gather -> bf16 means; MFMA dual-GEMM -> z (bf16, relu) ----
    aggregate_kernel<0><<<NV * 16 / 256, 256, 0, stream>>>(emb_gene, rs_var, esrc_gv, agg_var, NV);
    aggregate_kernel<0><<<NG * 16 / 256, 256, 0, stream>>>(emb_var, rs_gene, esrc_vg, agg_gene, NG);
    mfma_gemm_kernel<1, 1, 1><<<GB_V, 256, 0, stream>>>(agg_var, emb_var,
        Wl1_gv, Wr1_gv, bl1_gv, nullptr, z_var, NV);
    mfma_gemm_kernel<1, 1, 1><<<GB_G, 256, 0, stream>>>(agg_gene, emb_gene,
        Wl1_vg, Wr1_vg, bl1_vg, nullptr, z_gene, NG);

    // ---- layer 2: bf16 gather -> bf16 means; MFMA dual-GEMM -> d_out (f32) ----
    aggregate_kernel<1><<<NV * 16 / 256, 256, 0, stream>>>(z_gene, rs_var, esrc_gv, agg_var, NV);
    aggregate_kernel<1><<<NG * 16 / 256, 256, 0, stream>>>(z_var, rs_gene, esrc_vg, agg_gene, NG);
    mfma_gemm_kernel<1, 0, 0><<<GB_V, 256, 0, stream>>>(agg_var, z_var,
        Wl2_gv, Wr2_gv, bl2_gv, out_var2, nullptr, NV);
    mfma_gemm_kernel<1, 0, 0><<<GB_G, 256, 0, stream>>>(agg_gene, z_gene,
        Wl2_vg, Wr2_vg, bl2_vg, out_gene2, g2b, NG);

    // ---- adversarial head ----
    mfma_gemm_kernel<0, 0, 1><<<GB_G, 256, 0, stream>>>(nullptr, g2b,
        A1, A1, b1, nullptr, hdn_b, NG);
    head2_kernel<<<(NG + 31) / 32, 256, 0, stream>>>(hdn_b, A2, b2, out_adv, NG);
}

// Round 6
// 587.902 us; speedup vs baseline: 1.0791x; 1.0791x over previous
//
#include <hip/hip_runtime.h>
#include <hip/hip_bf16.h>

typedef unsigned short u16;
typedef unsigned int u32;
typedef __attribute__((ext_vector_type(8))) short bf16x8;
typedef __attribute__((ext_vector_type(4))) float f32x4;

#define NG 100000
#define NV 200000
#define NE 500000
#define HD 128
#define NALL (NG + NV)          // combined node count: gene rows 0.., var rows NG..
#define EALL (2 * NE)

__device__ __forceinline__ float bflo(u32 w) { return __uint_as_float(w << 16); }
__device__ __forceinline__ float bfhi(u32 w) { return __uint_as_float(w & 0xffff0000u); }
__device__ __forceinline__ u16 f2bf(float f) {
    __hip_bfloat16 h = __float2bfloat16(f);
    u16 u; __builtin_memcpy(&u, &h, 2); return u;
}

// ---- convert both f32 tables into one combined bf16 table [gene; var] ----
__global__ __launch_bounds__(256) void cvt_kernel(const float* __restrict__ g,
                                                  const float* __restrict__ v,
                                                  u16* __restrict__ out) {
    size_t slot = (size_t)blockIdx.x * 256 + threadIdx.x;   // 8 elems per slot
    size_t off = slot * 8;
    if (off >= (size_t)NALL * HD) return;
    const float* p = (off < (size_t)NG * HD) ? (g + off) : (v + (off - (size_t)NG * HD));
    float4 a = *(const float4*)p;
    float4 b = *(const float4*)(p + 4);
    uint4 pk;
    pk.x = (u32)f2bf(a.x) | ((u32)f2bf(a.y) << 16);
    pk.y = (u32)f2bf(a.z) | ((u32)f2bf(a.w) << 16);
    pk.z = (u32)f2bf(b.x) | ((u32)f2bf(b.y) << 16);
    pk.w = (u32)f2bf(b.z) | ((u32)f2bf(b.w) << 16);
    *(uint4*)(out + off) = pk;
}

// ---- combined histogram over both edge lists: dst var -> [0,NV), gene -> NV+ ----
__global__ __launch_bounds__(256) void hist2_kernel(const int* __restrict__ dst_gv,
                                                    const int* __restrict__ dst_vg,
                                                    int* __restrict__ deg) {
    int t = blockIdx.x * 256 + threadIdx.x;
    if (t < NE)            atomicAdd(&deg[dst_gv[t]], 1);
    else if (t < EALL)     atomicAdd(&deg[NV + dst_vg[t - NE]], 1);
}

// ---- scan stage 1: per-block (2048) exclusive scan + block sums ----
__global__ __launch_bounds__(256) void scan1_kernel(const int* __restrict__ deg,
                                                    int* __restrict__ excl,
                                                    int* __restrict__ bsum, int N) {
    __shared__ int lds[256];
    int tid = threadIdx.x;
    int base = blockIdx.x * 2048 + tid * 8;
    int v[8]; int s = 0;
#pragma unroll
    for (int i = 0; i < 8; ++i) { v[i] = (base + i < N) ? deg[base + i] : 0; s += v[i]; }
    lds[tid] = s;
    __syncthreads();
    for (int off = 1; off < 256; off <<= 1) {
        int x = (tid >= off) ? lds[tid - off] : 0;
        __syncthreads();
        lds[tid] += x;
        __syncthreads();
    }
    int run = lds[tid] - s;
#pragma unroll
    for (int i = 0; i < 8; ++i) {
        if (base + i < N) excl[base + i] = run;
        run += v[i];
    }
    if (tid == 255) bsum[blockIdx.x] = lds[255];
}

__global__ void scan2_kernel(int* __restrict__ bsum, int nb) {
    if (threadIdx.x == 0 && blockIdx.x == 0) {
        int run = 0;
        for (int i = 0; i < nb; ++i) { int t = bsum[i]; bsum[i] = run; run += t; }
    }
}

__global__ __launch_bounds__(256) void scan3_kernel(int* __restrict__ rs,
                                                    int* __restrict__ cur,
                                                    const int* __restrict__ bsum, int N) {
    int i = blockIdx.x * 256 + threadIdx.x;
    if (i < N) {
        int v = rs[i] + bsum[i >> 11];
        rs[i] = v;
        cur[i] = v;
    }
    if (i == 0) rs[N] = EALL;
}

// ---- combined edge scatter; esrc stored pre-offset into the combined table ----
// var-dst edges: source is gene -> esrc = src_gv (rows 0..NG-1)
// gene-dst edges: source is var -> esrc = NG + src_vg
__global__ __launch_bounds__(256) void escatter2_kernel(const int* __restrict__ src_gv,
                                                        const int* __restrict__ dst_gv,
                                                        const int* __restrict__ src_vg,
                                                        const int* __restrict__ dst_vg,
                                                        int* __restrict__ cur,
                                                        int* __restrict__ esrc) {
    int t = blockIdx.x * 256 + threadIdx.x;
    if (t < NE) {
        int p = atomicAdd(&cur[dst_gv[t]], 1);
        esrc[p] = src_gv[t];
    } else if (t < EALL) {
        int e = t - NE;
        int p = atomicAdd(&cur[NV + dst_vg[e]], 1);
        esrc[p] = NG + src_vg[e];
    }
}

// ---- gather-mean aggregate over the combined graph (uniform, branch-free) ----
// aggb row r (r<NV: var dst, else gene dst) = mean of X[esrc[e]] rows, bf16.
__global__ __launch_bounds__(256) void aggregate_kernel(const u16* __restrict__ X,
                                                        const int* __restrict__ rs,
                                                        const int* __restrict__ esrc,
                                                        u16* __restrict__ aggb) {
    u32 t = blockIdx.x * 256 + threadIdx.x;
    int row = t >> 4, c = t & 15;
    if (row >= NALL) return;
    int e0 = rs[row], e1 = rs[row + 1];
    float s[8] = {0.f, 0.f, 0.f, 0.f, 0.f, 0.f, 0.f, 0.f};
    for (int e = e0; e < e1; ++e) {
        const u16* p = X + (size_t)esrc[e] * HD + c * 8;
        uint4 u = *(const uint4*)p;
        u32 w[4] = {u.x, u.y, u.z, u.w};
#pragma unroll
        for (int i = 0; i < 4; ++i) { s[2 * i] += bflo(w[i]); s[2 * i + 1] += bfhi(w[i]); }
    }
    float rcv = 1.f / fmaxf((float)(e1 - e0), 1.f);
    uint4 pk;
    pk.x = (u32)f2bf(s[0] * rcv) | ((u32)f2bf(s[1] * rcv) << 16);
    pk.y = (u32)f2bf(s[2] * rcv) | ((u32)f2bf(s[3] * rcv) << 16);
    pk.z = (u32)f2bf(s[4] * rcv) | ((u32)f2bf(s[5] * rcv) << 16);
    pk.w = (u32)f2bf(s[6] * rcv) | ((u32)f2bf(s[7] * rcv) << 16);
    *(uint4*)(aggb + (size_t)row * HD + c * 8) = pk;
}

// ---- merged dual-segment MFMA SAGE linear (one dispatch per layer) ----
// blocks [0, nvb): var segment; [nvb, nvb+ngb): gene segment.
// out = act( Agg @ Wl^T + X @ Wr^T + b ), all inputs bf16, W f32->bf16 staged
// per phase in a 32 KB fragment-linear LDS buffer.
// Fragment map (m89-verified): A row=lane&15, k=8*(lane>>4)+j; B col=lane&15;
// D col=lane&15, row=4*(lane>>4)+reg.
template <int RELU>
__global__ __launch_bounds__(256, 4) void sage_mfma2_kernel(
    const u16* __restrict__ aggb,   // [NV+NG][HD] (var rows first)
    const u16* __restrict__ Xb,     // combined [gene; var] table
    const float* __restrict__ Wl_v, const float* __restrict__ Wr_v, const float* __restrict__ b_v,
    const float* __restrict__ Wl_g, const float* __restrict__ Wr_g, const float* __restrict__ b_g,
    float* __restrict__ outf_v, u16* __restrict__ outb_v,
    float* __restrict__ outf_g, u16* __restrict__ outb_g,
    int nvb)
{
    __shared__ u16 wlds[32][64][8];  // [frag=kt*8+ct][lane][8] : 32 KB
    const bool isVar = (int)blockIdx.x < nvb;
    const int bseg = isVar ? blockIdx.x : blockIdx.x - nvb;
    const int Nseg = isVar ? NV : NG;
    const u16* Aseg = aggb + (size_t)(isVar ? 0 : NV) * HD;
    const u16* Xseg = Xb + (size_t)(isVar ? NG : 0) * HD;
    const float* Wl = isVar ? Wl_v : Wl_g;
    const float* Wr = isVar ? Wr_v : Wr_g;
    const float* bias = isVar ? b_v : b_g;
    float* outf = isVar ? outf_v : outf_g;
    u16* outb = isVar ? outb_v : outb_g;

    const int tid = threadIdx.x;
    const int lane = tid & 63;
    const int wid = tid >> 6;
    const int m0 = bseg * 128 + wid * 32;
    const int lr = lane & 15, lg = lane >> 4;

    f32x4 acc[2][8];
#pragma unroll
    for (int rt = 0; rt < 2; ++rt)
#pragma unroll
        for (int ct = 0; ct < 8; ++ct) acc[rt][ct] = (f32x4){0.f, 0.f, 0.f, 0.f};

#pragma unroll
    for (int ph = 0; ph < 2; ++ph) {
        if (ph) __syncthreads();
        {   // stage this phase's W: f32 -> bf16, fragment-linear
            const float* W = ph == 0 ? Wl : Wr;
#pragma unroll
            for (int it = 0; it < 8; ++it) {
                int slot = it * 256 + tid;
                int f = slot >> 6, l = slot & 63;
                int kt = f >> 3, ct = f & 7;
                int row = ct * 16 + (l & 15);
                int kof = kt * 32 + (l >> 4) * 8;
                const float* wp = W + (size_t)row * HD + kof;
                float4 x = *(const float4*)wp;
                float4 y = *(const float4*)(wp + 4);
                uint4 pk;
                pk.x = (u32)f2bf(x.x) | ((u32)f2bf(x.y) << 16);
                pk.y = (u32)f2bf(x.z) | ((u32)f2bf(x.w) << 16);
                pk.z = (u32)f2bf(y.x) | ((u32)f2bf(y.y) << 16);
                pk.w = (u32)f2bf(y.z) | ((u32)f2bf(y.w) << 16);
                *(uint4*)&wlds[f][l][0] = pk;
            }
        }
        __syncthreads();
        const u16* A = (ph == 0) ? Aseg : Xseg;
#pragma unroll
        for (int kt = 0; kt < 4; ++kt) {
            bf16x8 a[2];
#pragma unroll
            for (int rt = 0; rt < 2; ++rt) {
                int row = m0 + rt * 16 + lr; if (row > Nseg - 1) row = Nseg - 1;
                a[rt] = *(const bf16x8*)(A + (size_t)row * HD + kt * 32 + lg * 8);
            }
#pragma unroll
            for (int ct = 0; ct < 8; ++ct) {
                bf16x8 wfrag = *(const bf16x8*)&wlds[kt * 8 + ct][lane][0];
#pragma unroll
                for (int rt = 0; rt < 2; ++rt)
                    acc[rt][ct] = __builtin_amdgcn_mfma_f32_16x16x32_bf16(
                        a[rt], wfrag, acc[rt][ct], 0, 0, 0);
            }
        }
    }

    // epilogue: + bias, relu, store
#pragma unroll
    for (int ct = 0; ct < 8; ++ct) {
        int col = ct * 16 + lr;
        float bcol = bias[col];
#pragma unroll
        for (int rt = 0; rt < 2; ++rt) {
            int rb = m0 + rt * 16 + lg * 4;
#pragma unroll
            for (int r = 0; r < 4; ++r) {
                int row = rb + r;
                if (row >= Nseg) continue;
                float v = acc[rt][ct][r] + bcol;
                if (RELU) v = fmaxf(v, 0.f);
                if (outf) outf[(size_t)row * HD + col] = v;
                if (outb) outb[(size_t)row * HD + col] = f2bf(v);
            }
        }
    }
}

// ---- single-phase MFMA GEMM for head stage 1: hdn = relu(g2b @ A1^T + b1) ----
__global__ __launch_bounds__(256, 4) void head1_kernel(
    const u16* __restrict__ Xb,
    const float* __restrict__ W, const float* __restrict__ bias,
    u16* __restrict__ outb, int N)
{
    __shared__ u16 wlds[32][64][8];
    const int tid = threadIdx.x;
    const int lane = tid & 63;
    const int wid = tid >> 6;
    const int m0 = blockIdx.x * 128 + wid * 32;
    const int lr = lane & 15, lg = lane >> 4;

#pragma unroll
    for (int it = 0; it < 8; ++it) {
        int slot = it * 256 + tid;
        int f = slot >> 6, l = slot & 63;
        int kt = f >> 3, ct = f & 7;
        int row = ct * 16 + (l & 15);
        int kof = kt * 32 + (l >> 4) * 8;
        const float* wp = W + (size_t)row * HD + kof;
        float4 x = *(const float4*)wp;
        float4 y = *(const float4*)(wp + 4);
        uint4 pk;
        pk.x = (u32)f2bf(x.x) | ((u32)f2bf(x.y) << 16);
        pk.y = (u32)f2bf(x.z) | ((u32)f2bf(x.w) << 16);
        pk.z = (u32)f2bf(y.x) | ((u32)f2bf(y.y) << 16);
        pk.w = (u32)f2bf(y.z) | ((u32)f2bf(y.w) << 16);
        *(uint4*)&wlds[f][l][0] = pk;
    }
    __syncthreads();

    f32x4 acc[2][8];
#pragma unroll
    for (int rt = 0; rt < 2; ++rt)
#pragma unroll
        for (int ct = 0; ct < 8; ++ct) acc[rt][ct] = (f32x4){0.f, 0.f, 0.f, 0.f};

#pragma unroll
    for (int kt = 0; kt < 4; ++kt) {
        bf16x8 a[2];
#pragma unroll
        for (int rt = 0; rt < 2; ++rt) {
            int row = m0 + rt * 16 + lr; if (row > N - 1) row = N - 1;
            a[rt] = *(const bf16x8*)(Xb + (size_t)row * HD + kt * 32 + lg * 8);
        }
#pragma unroll
        for (int ct = 0; ct < 8; ++ct) {
            bf16x8 wfrag = *(const bf16x8*)&wlds[kt * 8 + ct][lane][0];
#pragma unroll
            for (int rt = 0; rt < 2; ++rt)
                acc[rt][ct] = __builtin_amdgcn_mfma_f32_16x16x32_bf16(
                    a[rt], wfrag, acc[rt][ct], 0, 0, 0);
        }
    }
#pragma unroll
    for (int ct = 0; ct < 8; ++ct) {
        int col = ct * 16 + lr;
        float bcol = bias[col];
#pragma unroll
        for (int rt = 0; rt < 2; ++rt) {
            int rb = m0 + rt * 16 + lg * 4;
#pragma unroll
            for (int r = 0; r < 4; ++r) {
                int row = rb + r;
                if (row >= N) continue;
                float v = fmaxf(acc[rt][ct][r] + bcol, 0.f);
                outb[(size_t)row * HD + col] = f2bf(v);
            }
        }
    }
}

// ---- adversarial head stage 2: adv = hdn @ A2^T + b2  (128 -> 8), hdn bf16 ----
__global__ __launch_bounds__(256) void head2_kernel(const u16* __restrict__ hdn,
                                                    const float* __restrict__ A2,
                                                    const float* __restrict__ b2,
                                                    float* __restrict__ adv, int N)
{
    int tid = threadIdx.x;
    int r = blockIdx.x * 32 + (tid >> 3);
    int o = tid & 7;
    if (r >= N) return;
    const u16* hp = hdn + (size_t)r * HD;
    const float* ap = A2 + (size_t)o * HD;
    float acc = 0.f;
#pragma unroll 4
    for (int k = 0; k < HD; k += 8) {
        uint4 u = *(const uint4*)(hp + k);
        float4 a0 = *(const float4*)(ap + k);
        float4 a1 = *(const float4*)(ap + k + 4);
        u32 w[4] = {u.x, u.y, u.z, u.w};
        acc = fmaf(bflo(w[0]), a0.x, acc); acc = fmaf(bfhi(w[0]), a0.y, acc);
        acc = fmaf(bflo(w[1]), a0.z, acc); acc = fmaf(bfhi(w[1]), a0.w, acc);
        acc = fmaf(bflo(w[2]), a1.x, acc); acc = fmaf(bfhi(w[2]), a1.y, acc);
        acc = fmaf(bflo(w[3]), a1.z, acc); acc = fmaf(bfhi(w[3]), a1.w, acc);
    }
    adv[(size_t)r * 8 + o] = acc + b2[o];
}

extern "C" void kernel_launch(void* const* d_in, const int* in_sizes, int n_in,
                              void* d_out, int out_size, void* d_ws, size_t ws_size,
                              hipStream_t stream)
{
    const float* emb_gene = (const float*)d_in[0];
    const float* emb_var  = (const float*)d_in[1];
    const float* Wl1_gv = (const float*)d_in[2];
    const float* bl1_gv = (const float*)d_in[3];
    const float* Wr1_gv = (const float*)d_in[4];
    const float* Wl1_vg = (const float*)d_in[5];
    const float* bl1_vg = (const float*)d_in[6];
    const float* Wr1_vg = (const float*)d_in[7];
    const float* Wl2_gv = (const float*)d_in[8];
    const float* bl2_gv = (const float*)d_in[9];
    const float* Wr2_gv = (const float*)d_in[10];
    const float* Wl2_vg = (const float*)d_in[11];
    const float* bl2_vg = (const float*)d_in[12];
    const float* Wr2_vg = (const float*)d_in[13];
    const float* A1 = (const float*)d_in[14];
    const float* b1 = (const float*)d_in[15];
    const float* A2 = (const float*)d_in[16];
    const float* b2 = (const float*)d_in[17];
    const int* src_gv = (const int*)d_in[18];
    const int* dst_gv = (const int*)d_in[19];
    const int* src_vg = (const int*)d_in[20];
    const int* dst_vg = (const int*)d_in[21];

    // ws layout (bytes) — total ~289.3 MB; ws_size ≈ 627 MB (measured via the
    // harness poison fill WRITE_SIZE = 612,500 KB in round-5 profile):
    char* ws = (char*)d_ws;
    u16* embb = (u16*)(ws);                  // bf16 [NALL][128] gene;var  76.8 MB
    u16* zb   = (u16*)(ws + 76800000);       // bf16 [NALL][128] gene;var  76.8 MB
    u16* aggb = (u16*)(ws + 153600000);      // bf16 [NALL][128] var;gene  76.8 MB
    u16* g2b  = (u16*)(ws + 230400000);      // bf16 [NG][128]             25.6 MB
    u16* hdnb = (u16*)(ws + 256000000);      // bf16 [NG][128]             25.6 MB
    int* rs   = (int*)(ws + 281600000);      // [NALL+1]
    int* esrc = (int*)(ws + 282900000);      // [2E]
    int* deg  = (int*)(ws + 286900000);      // [NALL] transient
    int* cur  = (int*)(ws + 288100000);      // [NALL] transient
    int* bsum = (int*)(ws + 289300000);      // [147]

    float* out       = (float*)d_out;
    float* out_gene2 = out;                          // [NG][128]
    float* out_var2  = out + (size_t)NG * HD;        // [NV][128]
    float* out_adv   = out + (size_t)(NG + NV) * HD; // [NG][8]

    const int NB = (NALL + 2047) / 2048;   // 147
    const int EB2 = (EALL + 255) / 256;    // 3907
    const int NVB = (NV + 127) / 128;      // 1563
    const int NGB = (NG + 127) / 128;      // 782
    const int CVB = (int)(((size_t)NALL * HD / 8 + 255) / 256);  // 18750

    // ---- prep: bf16 tables + CSR over combined graph ----
    hipMemsetAsync(deg, 0, (size_t)NALL * 4, stream);
    cvt_kernel<<<CVB, 256, 0, stream>>>(emb_gene, emb_var, embb);
    hist2_kernel<<<EB2, 256, 0, stream>>>(dst_gv, dst_vg, deg);
    scan1_kernel<<<NB, 256, 0, stream>>>(deg, rs, bsum, NALL);
    scan2_kernel<<<1, 64, 0, stream>>>(bsum, NB);
    scan3_kernel<<<(NALL + 255) / 256, 256, 0, stream>>>(rs, cur, bsum, NALL);
    escatter2_kernel<<<EB2, 256, 0, stream>>>(src_gv, dst_gv, src_vg, dst_vg, cur, esrc);

    // ---- layer 1 ----
    aggregate_kernel<<<NALL * 16 / 256, 256, 0, stream>>>(embb, rs, esrc, aggb);
    sage_mfma2_kernel<1><<<NVB + NGB, 256, 0, stream>>>(aggb, embb,
        Wl1_gv, Wr1_gv, bl1_gv, Wl1_vg, Wr1_vg, bl1_vg,
        nullptr, zb + (size_t)NG * HD,   // var -> z var rows
        nullptr, zb,                     // gene -> z gene rows
        NVB);

    // ---- layer 2 ----
    aggregate_kernel<<<NALL * 16 / 256, 256, 0, stream>>>(zb, rs, esrc, aggb);
    sage_mfma2_kernel<0><<<NVB + NGB, 256, 0, stream>>>(aggb, zb,
        Wl2_gv, Wr2_gv, bl2_gv, Wl2_vg, Wr2_vg, bl2_vg,
        out_var2, nullptr,
        out_gene2, g2b,
        NVB);

    // ---- adversarial head ----
    head1_kernel<<<NGB, 256, 0, stream>>>(g2b, A1, b1, hdnb, NG);
    head2_kernel<<<(NG + 31) / 32, 256, 0, stream>>>(hdnb, A2, b2, out_adv, NG);
}

// Round 7
// 491.652 us; speedup vs baseline: 1.2903x; 1.1958x over previous
//
#include <hip/hip_runtime.h>
#include <hip/hip_bf16.h>

typedef unsigned short u16;
typedef unsigned int u32;
typedef __attribute__((ext_vector_type(8))) short bf16x8;
typedef __attribute__((ext_vector_type(4))) float f32x4;

#define NG 100000
#define NV 200000
#define NE 500000
#define HD 128
#define NALL (NG + NV)          // combined node count: gene rows 0.., var rows NG..
#define EALL (2 * NE)

__device__ __forceinline__ float bflo(u32 w) { return __uint_as_float(w << 16); }
__device__ __forceinline__ float bfhi(u32 w) { return __uint_as_float(w & 0xffff0000u); }
__device__ __forceinline__ u16 f2bf(float f) {
    __hip_bfloat16 h = __float2bfloat16(f);
    u16 u; __builtin_memcpy(&u, &h, 2); return u;
}
__device__ __forceinline__ u32 pk2(float a, float b) {
    return (u32)f2bf(a) | ((u32)f2bf(b) << 16);
}

// ---- convert both f32 tables into one combined bf16 table [gene; var] ----
__global__ __launch_bounds__(256) void cvt_kernel(const float* __restrict__ g,
                                                  const float* __restrict__ v,
                                                  u16* __restrict__ out) {
    size_t slot = (size_t)blockIdx.x * 256 + threadIdx.x;   // 8 elems per slot
    size_t off = slot * 8;
    if (off >= (size_t)NALL * HD) return;
    const float* p = (off < (size_t)NG * HD) ? (g + off) : (v + (off - (size_t)NG * HD));
    float4 a = *(const float4*)p;
    float4 b = *(const float4*)(p + 4);
    uint4 pk;
    pk.x = pk2(a.x, a.y); pk.y = pk2(a.z, a.w);
    pk.z = pk2(b.x, b.y); pk.w = pk2(b.z, b.w);
    *(uint4*)(out + off) = pk;
}

// ---- convert 9 weight matrices f32 [128][128] -> fragment-ordered bf16 ----
// Fragment layout (matches MFMA B-frag): buf[f=kt*8+ct][lane][8] where
// row = ct*16 + (lane&15), k = kt*32 + (lane>>4)*8 + j.  One block per matrix.
__global__ __launch_bounds__(256) void wcvt_kernel(
    const float* w0, const float* w1, const float* w2, const float* w3,
    const float* w4, const float* w5, const float* w6, const float* w7,
    const float* w8, u16* __restrict__ out)
{
    const float* Ws[9] = {w0, w1, w2, w3, w4, w5, w6, w7, w8};
    const float* W = Ws[blockIdx.x];
    u16* o = out + (size_t)blockIdx.x * 16384;
    int tid = threadIdx.x;
#pragma unroll
    for (int it = 0; it < 8; ++it) {
        int slot = it * 256 + tid;       // 0..2047
        int f = slot >> 6, l = slot & 63;
        int kt = f >> 3, ct = f & 7;
        int row = ct * 16 + (l & 15);
        int kof = kt * 32 + (l >> 4) * 8;
        const float* wp = W + (size_t)row * HD + kof;
        float4 x = *(const float4*)wp;
        float4 y = *(const float4*)(wp + 4);
        uint4 pk;
        pk.x = pk2(x.x, x.y); pk.y = pk2(x.z, x.w);
        pk.z = pk2(y.x, y.y); pk.w = pk2(y.z, y.w);
        *(uint4*)(o + (size_t)slot * 8) = pk;
    }
}

// ---- combined histogram over both edge lists: dst var -> [0,NV), gene -> NV+ ----
__global__ __launch_bounds__(256) void hist2_kernel(const int* __restrict__ dst_gv,
                                                    const int* __restrict__ dst_vg,
                                                    int* __restrict__ deg) {
    int t = blockIdx.x * 256 + threadIdx.x;
    if (t < NE)            atomicAdd(&deg[dst_gv[t]], 1);
    else if (t < EALL)     atomicAdd(&deg[NV + dst_vg[t - NE]], 1);
}

// ---- scan stage 1: per-block (2048) exclusive scan + block sums ----
__global__ __launch_bounds__(256) void scan1_kernel(const int* __restrict__ deg,
                                                    int* __restrict__ excl,
                                                    int* __restrict__ bsum, int N) {
    __shared__ int lds[256];
    int tid = threadIdx.x;
    int base = blockIdx.x * 2048 + tid * 8;
    int v[8]; int s = 0;
#pragma unroll
    for (int i = 0; i < 8; ++i) { v[i] = (base + i < N) ? deg[base + i] : 0; s += v[i]; }
    lds[tid] = s;
    __syncthreads();
    for (int off = 1; off < 256; off <<= 1) {
        int x = (tid >= off) ? lds[tid - off] : 0;
        __syncthreads();
        lds[tid] += x;
        __syncthreads();
    }
    int run = lds[tid] - s;
#pragma unroll
    for (int i = 0; i < 8; ++i) {
        if (base + i < N) excl[base + i] = run;
        run += v[i];
    }
    if (tid == 255) bsum[blockIdx.x] = lds[255];
}

__global__ void scan2_kernel(int* __restrict__ bsum, int nb) {
    if (threadIdx.x == 0 && blockIdx.x == 0) {
        int run = 0;
        for (int i = 0; i < nb; ++i) { int t = bsum[i]; bsum[i] = run; run += t; }
    }
}

__global__ __launch_bounds__(256) void scan3_kernel(int* __restrict__ rs,
                                                    int* __restrict__ cur,
                                                    const int* __restrict__ bsum, int N) {
    int i = blockIdx.x * 256 + threadIdx.x;
    if (i < N) {
        int v = rs[i] + bsum[i >> 11];
        rs[i] = v;
        cur[i] = v;
    }
    if (i == 0) rs[N] = EALL;
}

// ---- combined edge scatter; esrc stored pre-offset into the combined table ----
__global__ __launch_bounds__(256) void escatter2_kernel(const int* __restrict__ src_gv,
                                                        const int* __restrict__ dst_gv,
                                                        const int* __restrict__ src_vg,
                                                        const int* __restrict__ dst_vg,
                                                        int* __restrict__ cur,
                                                        int* __restrict__ esrc) {
    int t = blockIdx.x * 256 + threadIdx.x;
    if (t < NE) {
        int p = atomicAdd(&cur[dst_gv[t]], 1);
        esrc[p] = src_gv[t];
    } else if (t < EALL) {
        int e = t - NE;
        int p = atomicAdd(&cur[NV + dst_vg[e]], 1);
        esrc[p] = NG + src_vg[e];
    }
}

// ---- gather-mean aggregate over the combined graph (uniform, branch-free) ----
__global__ __launch_bounds__(256) void aggregate_kernel(const u16* __restrict__ X,
                                                        const int* __restrict__ rs,
                                                        const int* __restrict__ esrc,
                                                        u16* __restrict__ aggb) {
    u32 t = blockIdx.x * 256 + threadIdx.x;
    int row = t >> 4, c = t & 15;
    if (row >= NALL) return;
    int e0 = rs[row], e1 = rs[row + 1];
    float s[8] = {0.f, 0.f, 0.f, 0.f, 0.f, 0.f, 0.f, 0.f};
    for (int e = e0; e < e1; ++e) {
        const u16* p = X + (size_t)esrc[e] * HD + c * 8;
        uint4 u = *(const uint4*)p;
        u32 w[4] = {u.x, u.y, u.z, u.w};
#pragma unroll
        for (int i = 0; i < 4; ++i) { s[2 * i] += bflo(w[i]); s[2 * i + 1] += bfhi(w[i]); }
    }
    float rcv = 1.f / fmaxf((float)(e1 - e0), 1.f);
    uint4 pk;
    pk.x = pk2(s[0] * rcv, s[1] * rcv);
    pk.y = pk2(s[2] * rcv, s[3] * rcv);
    pk.z = pk2(s[4] * rcv, s[5] * rcv);
    pk.w = pk2(s[6] * rcv, s[7] * rcv);
    *(uint4*)(aggb + (size_t)row * HD + c * 8) = pk;
}

// ---- merged dual-segment MFMA SAGE linear, LDS-free W path ----
// W fragments pre-converted in global (wcvt). A-frags prefetched per phase.
// Epilogue: per-wave LDS transpose -> coalesced f32x4 / uint4 stores.
// Fragment map (m89-verified): A row=lane&15, k=8*(lane>>4)+j; B col=lane&15;
// D col=lane&15, row=4*(lane>>4)+reg.
template <int RELU, int OBF16>
__global__ __launch_bounds__(256, 4) void sage_mfma2_kernel(
    const u16* __restrict__ aggb,   // [NV+NG][HD] (var rows first)
    const u16* __restrict__ Xb,     // combined [gene; var] table
    const u16* __restrict__ wf_v,   // frag bufs: Wl at +0, Wr at +16384
    const u16* __restrict__ wf_g,
    const float* __restrict__ b_v, const float* __restrict__ b_g,
    float* __restrict__ outf_v, float* __restrict__ outf_g,
    u16* __restrict__ outb_v, u16* __restrict__ outb_g,
    int nvb)
{
    __shared__ __align__(16) float lds_t[4][16][132];
    const bool isVar = (int)blockIdx.x < nvb;
    const int bseg = isVar ? blockIdx.x : blockIdx.x - nvb;
    const int Nseg = isVar ? NV : NG;
    const u16* Aseg = aggb + (size_t)(isVar ? 0 : NV) * HD;
    const u16* Xseg = Xb + (size_t)(isVar ? NG : 0) * HD;
    const u16* wf = isVar ? wf_v : wf_g;
    const float* bias = isVar ? b_v : b_g;
    float* outf = isVar ? outf_v : outf_g;
    u16* outb = isVar ? outb_v : outb_g;

    const int tid = threadIdx.x;
    const int lane = tid & 63;
    const int wid = tid >> 6;
    const int m0 = bseg * 128 + wid * 32;
    const int lr = lane & 15, lg = lane >> 4;

    f32x4 acc[2][8];
#pragma unroll
    for (int rt = 0; rt < 2; ++rt)
#pragma unroll
        for (int ct = 0; ct < 8; ++ct) acc[rt][ct] = (f32x4){0.f, 0.f, 0.f, 0.f};

#pragma unroll
    for (int ph = 0; ph < 2; ++ph) {
        const u16* A = (ph == 0) ? Aseg : Xseg;
        const u16* wp = wf + ph * 16384;
        bf16x8 a[4][2];
#pragma unroll
        for (int kt = 0; kt < 4; ++kt)
#pragma unroll
            for (int rt = 0; rt < 2; ++rt) {
                int row = m0 + rt * 16 + lr; if (row > Nseg - 1) row = Nseg - 1;
                a[kt][rt] = *(const bf16x8*)(A + (size_t)row * HD + kt * 32 + lg * 8);
            }
#pragma unroll
        for (int kt = 0; kt < 4; ++kt)
#pragma unroll
            for (int ct = 0; ct < 8; ++ct) {
                bf16x8 w = *(const bf16x8*)(wp + (size_t)(((kt * 8 + ct) << 6) + lane) * 8);
#pragma unroll
                for (int rt = 0; rt < 2; ++rt)
                    acc[rt][ct] = __builtin_amdgcn_mfma_f32_16x16x32_bf16(
                        a[kt][rt], w, acc[rt][ct], 0, 0, 0);
            }
    }

    float bv[8];
#pragma unroll
    for (int ct = 0; ct < 8; ++ct) bv[ct] = bias[ct * 16 + lr];

#pragma unroll
    for (int rt = 0; rt < 2; ++rt) {
#pragma unroll
        for (int ct = 0; ct < 8; ++ct)
#pragma unroll
            for (int r = 0; r < 4; ++r) {
                float v = acc[rt][ct][r] + bv[ct];
                if (RELU) v = fmaxf(v, 0.f);
                lds_t[wid][lg * 4 + r][ct * 16 + lr] = v;
            }
        __syncthreads();
        if (OBF16 == 0) {
#pragma unroll
            for (int i = 0; i < 8; ++i) {
                int row16 = i * 2 + (lane >> 5);
                int colb = (lane & 31) * 4;
                f32x4 v = *(const f32x4*)&lds_t[wid][row16][colb];
                int grow = m0 + rt * 16 + row16;
                if (grow < Nseg) *(f32x4*)(outf + (size_t)grow * HD + colb) = v;
            }
        } else {
#pragma unroll
            for (int i = 0; i < 4; ++i) {
                int row16 = i * 4 + (lane >> 4);
                int colb = (lane & 15) * 8;
                f32x4 v0 = *(const f32x4*)&lds_t[wid][row16][colb];
                f32x4 v1 = *(const f32x4*)&lds_t[wid][row16][colb + 4];
                uint4 pk;
                pk.x = pk2(v0[0], v0[1]); pk.y = pk2(v0[2], v0[3]);
                pk.z = pk2(v1[0], v1[1]); pk.w = pk2(v1[2], v1[3]);
                int grow = m0 + rt * 16 + row16;
                if (grow < Nseg) *(uint4*)(outb + (size_t)grow * HD + colb) = pk;
            }
        }
        __syncthreads();
    }
}

// ---- fused adversarial head: adv = relu(g2 @ A1^T + b1) @ A2^T + b2 ----
// Stage 1 acc (bias+relu) staged per-wave to LDS as bf16, re-read as MFMA
// A-frags, multiplied by in-register A2 B-frag (cols 8..15 zero).
__global__ __launch_bounds__(256, 4) void head_kernel(
    const float* __restrict__ g2,     // f32 [NG][128] (out_gene2)
    const u16* __restrict__ wfA1,     // A1 frag buf
    const float* __restrict__ b1,
    const float* __restrict__ A2,     // f32 [8][128]
    const float* __restrict__ b2,
    float* __restrict__ adv)          // f32 [NG][8]
{
    __shared__ __align__(16) u16 lds_h[4][16][136];
    const int tid = threadIdx.x;
    const int lane = tid & 63;
    const int wid = tid >> 6;
    const int m0 = blockIdx.x * 128 + wid * 32;
    const int lr = lane & 15, lg = lane >> 4;

    // A2 B-fragments: col=lr (valid <8), k = kt*32 + lg*8 + j
    bf16x8 a2f[4];
#pragma unroll
    for (int kt = 0; kt < 4; ++kt) {
        union { u16 s[8]; bf16x8 v; } u;
        if (lr < 8) {
            const float* p = A2 + (size_t)lr * HD + kt * 32 + lg * 8;
            float4 x = *(const float4*)p;
            float4 y = *(const float4*)(p + 4);
            u.s[0] = f2bf(x.x); u.s[1] = f2bf(x.y); u.s[2] = f2bf(x.z); u.s[3] = f2bf(x.w);
            u.s[4] = f2bf(y.x); u.s[5] = f2bf(y.y); u.s[6] = f2bf(y.z); u.s[7] = f2bf(y.w);
        } else {
#pragma unroll
            for (int i = 0; i < 8; ++i) u.s[i] = 0;
        }
        a2f[kt] = u.v;
    }

    f32x4 acc[2][8];
#pragma unroll
    for (int rt = 0; rt < 2; ++rt)
#pragma unroll
        for (int ct = 0; ct < 8; ++ct) acc[rt][ct] = (f32x4){0.f, 0.f, 0.f, 0.f};

#pragma unroll
    for (int kt = 0; kt < 4; ++kt) {
        bf16x8 a[2];
#pragma unroll
        for (int rt = 0; rt < 2; ++rt) {
            int row = m0 + rt * 16 + lr; if (row > NG - 1) row = NG - 1;
            const float* p = g2 + (size_t)row * HD + kt * 32 + lg * 8;
            float4 x = *(const float4*)p;
            float4 y = *(const float4*)(p + 4);
            union { u16 s[8]; bf16x8 v; } u;
            u.s[0] = f2bf(x.x); u.s[1] = f2bf(x.y); u.s[2] = f2bf(x.z); u.s[3] = f2bf(x.w);
            u.s[4] = f2bf(y.x); u.s[5] = f2bf(y.y); u.s[6] = f2bf(y.z); u.s[7] = f2bf(y.w);
            a[rt] = u.v;
        }
#pragma unroll
        for (int ct = 0; ct < 8; ++ct) {
            bf16x8 w = *(const bf16x8*)(wfA1 + (size_t)(((kt * 8 + ct) << 6) + lane) * 8);
#pragma unroll
            for (int rt = 0; rt < 2; ++rt)
                acc[rt][ct] = __builtin_amdgcn_mfma_f32_16x16x32_bf16(
                    a[rt], w, acc[rt][ct], 0, 0, 0);
        }
    }

    float b1v[8];
#pragma unroll
    for (int ct = 0; ct < 8; ++ct) b1v[ct] = b1[ct * 16 + lr];
    float b2v = (lr < 8) ? b2[lr] : 0.f;

#pragma unroll
    for (int rt = 0; rt < 2; ++rt) {
#pragma unroll
        for (int ct = 0; ct < 8; ++ct)
#pragma unroll
            for (int r = 0; r < 4; ++r) {
                float v = fmaxf(acc[rt][ct][r] + b1v[ct], 0.f);
                lds_h[wid][lg * 4 + r][ct * 16 + lr] = f2bf(v);
            }
        __syncthreads();
        f32x4 av = (f32x4){0.f, 0.f, 0.f, 0.f};
#pragma unroll
        for (int kt = 0; kt < 4; ++kt) {
            bf16x8 h = *(const bf16x8*)&lds_h[wid][lr][kt * 32 + lg * 8];
            av = __builtin_amdgcn_mfma_f32_16x16x32_bf16(h, a2f[kt], av, 0, 0, 0);
        }
        if (lr < 8) {
#pragma unroll
            for (int r = 0; r < 4; ++r) {
                int grow = m0 + rt * 16 + lg * 4 + r;
                if (grow < NG) adv[(size_t)grow * 8 + lr] = av[r] + b2v;
            }
        }
        __syncthreads();
    }
}

extern "C" void kernel_launch(void* const* d_in, const int* in_sizes, int n_in,
                              void* d_out, int out_size, void* d_ws, size_t ws_size,
                              hipStream_t stream)
{
    const float* emb_gene = (const float*)d_in[0];
    const float* emb_var  = (const float*)d_in[1];
    const float* Wl1_gv = (const float*)d_in[2];
    const float* bl1_gv = (const float*)d_in[3];
    const float* Wr1_gv = (const float*)d_in[4];
    const float* Wl1_vg = (const float*)d_in[5];
    const float* bl1_vg = (const float*)d_in[6];
    const float* Wr1_vg = (const float*)d_in[7];
    const float* Wl2_gv = (const float*)d_in[8];
    const float* bl2_gv = (const float*)d_in[9];
    const float* Wr2_gv = (const float*)d_in[10];
    const float* Wl2_vg = (const float*)d_in[11];
    const float* bl2_vg = (const float*)d_in[12];
    const float* Wr2_vg = (const float*)d_in[13];
    const float* A1 = (const float*)d_in[14];
    const float* b1 = (const float*)d_in[15];
    const float* A2 = (const float*)d_in[16];
    const float* b2 = (const float*)d_in[17];
    const int* src_gv = (const int*)d_in[18];
    const int* dst_gv = (const int*)d_in[19];
    const int* src_vg = (const int*)d_in[20];
    const int* dst_vg = (const int*)d_in[21];

    // ws layout (bytes) — total ~239 MB; ws_size ≈ 627 MB (measured r5 poison fill):
    char* ws = (char*)d_ws;
    u16* embb  = (u16*)(ws);                  // bf16 [NALL][128] gene;var  76.8 MB
    u16* zb    = (u16*)(ws + 76800000);       // bf16 [NALL][128] gene;var  76.8 MB
    u16* aggb  = (u16*)(ws + 153600000);      // bf16 [NALL][128] var;gene  76.8 MB
    u16* wfrag = (u16*)(ws + 230400000);      // 9 x 32 KB fragment bufs
    int* rs    = (int*)(ws + 230700000);      // [NALL+1]
    int* esrc  = (int*)(ws + 232000000);      // [2E]
    int* deg   = (int*)(ws + 236000000);      // [NALL] transient
    int* cur   = (int*)(ws + 237200000);      // [NALL] transient
    int* bsum  = (int*)(ws + 238400000);      // [147]

    float* out       = (float*)d_out;
    float* out_gene2 = out;                          // [NG][128]
    float* out_var2  = out + (size_t)NG * HD;        // [NV][128]
    float* out_adv   = out + (size_t)(NG + NV) * HD; // [NG][8]

    const int NB = (NALL + 2047) / 2048;   // 147
    const int EB2 = (EALL + 255) / 256;    // 3907
    const int NVB = (NV + 127) / 128;      // 1563
    const int NGB = (NG + 127) / 128;      // 782
    const int CVB = (int)(((size_t)NALL * HD / 8 + 255) / 256);  // 18750

    // ---- prep: bf16 tables + W fragment bufs + CSR over combined graph ----
    hipMemsetAsync(deg, 0, (size_t)NALL * 4, stream);
    cvt_kernel<<<CVB, 256, 0, stream>>>(emb_gene, emb_var, embb);
    wcvt_kernel<<<9, 256, 0, stream>>>(Wl1_gv, Wr1_gv, Wl1_vg, Wr1_vg,
                                       Wl2_gv, Wr2_gv, Wl2_vg, Wr2_vg, A1, wfrag);
    hist2_kernel<<<EB2, 256, 0, stream>>>(dst_gv, dst_vg, deg);
    scan1_kernel<<<NB, 256, 0, stream>>>(deg, rs, bsum, NALL);
    scan2_kernel<<<1, 64, 0, stream>>>(bsum, NB);
    scan3_kernel<<<(NALL + 255) / 256, 256, 0, stream>>>(rs, cur, bsum, NALL);
    escatter2_kernel<<<EB2, 256, 0, stream>>>(src_gv, dst_gv, src_vg, dst_vg, cur, esrc);

    // ---- layer 1: aggregate -> bf16 means; MFMA dual-GEMM -> zb (bf16, relu) ----
    aggregate_kernel<<<NALL * 16 / 256, 256, 0, stream>>>(embb, rs, esrc, aggb);
    sage_mfma2_kernel<1, 1><<<NVB + NGB, 256, 0, stream>>>(aggb, embb,
        wfrag + 0 * 16384, wfrag + 2 * 16384, bl1_gv, bl1_vg,
        nullptr, nullptr,
        zb + (size_t)NG * HD, zb,
        NVB);

    // ---- layer 2: aggregate bf16 z; MFMA dual-GEMM -> d_out (f32) ----
    aggregate_kernel<<<NALL * 16 / 256, 256, 0, stream>>>(zb, rs, esrc, aggb);
    sage_mfma2_kernel<0, 0><<<NVB + NGB, 256, 0, stream>>>(aggb, zb,
        wfrag + 4 * 16384, wfrag + 6 * 16384, bl2_gv, bl2_vg,
        out_var2, out_gene2,
        nullptr, nullptr,
        NVB);

    // ---- fused adversarial head ----
    head_kernel<<<NGB, 256, 0, stream>>>(out_gene2, wfrag + 8 * 16384, b1, A2, b2, out_adv);
}

// Round 8
// 477.331 us; speedup vs baseline: 1.3291x; 1.0300x over previous
//
#include <hip/hip_runtime.h>
#include <hip/hip_bf16.h>

typedef unsigned short u16;
typedef unsigned int u32;
typedef __attribute__((ext_vector_type(8))) short bf16x8;
typedef __attribute__((ext_vector_type(4))) float f32x4;

#define NG 100000
#define NV 200000
#define NE 500000
#define HD 128
#define NALL (NG + NV)          // combined node count: gene rows 0.., var rows NG..
#define EALL (2 * NE)

__device__ __forceinline__ float bflo(u32 w) { return __uint_as_float(w << 16); }
__device__ __forceinline__ float bfhi(u32 w) { return __uint_as_float(w & 0xffff0000u); }
__device__ __forceinline__ u16 f2bf(float f) {
    __hip_bfloat16 h = __float2bfloat16(f);
    u16 u; __builtin_memcpy(&u, &h, 2); return u;
}
__device__ __forceinline__ u32 pk2(float a, float b) {
    return (u32)f2bf(a) | ((u32)f2bf(b) << 16);
}

// ---- convert both f32 tables into one combined bf16 table [gene; var] ----
__global__ __launch_bounds__(256) void cvt_kernel(const float* __restrict__ g,
                                                  const float* __restrict__ v,
                                                  u16* __restrict__ out) {
    size_t slot = (size_t)blockIdx.x * 256 + threadIdx.x;   // 8 elems per slot
    size_t off = slot * 8;
    if (off >= (size_t)NALL * HD) return;
    const float* p = (off < (size_t)NG * HD) ? (g + off) : (v + (off - (size_t)NG * HD));
    float4 a = *(const float4*)p;
    float4 b = *(const float4*)(p + 4);
    uint4 pk;
    pk.x = pk2(a.x, a.y); pk.y = pk2(a.z, a.w);
    pk.z = pk2(b.x, b.y); pk.w = pk2(b.z, b.w);
    *(uint4*)(out + off) = pk;
}

// ---- convert 9 weight matrices f32 [128][128] -> fragment-ordered bf16 ----
// buf[f=kt*8+ct][lane][8]: row = ct*16 + (lane&15), k = kt*32 + (lane>>4)*8 + j.
__global__ __launch_bounds__(256) void wcvt_kernel(
    const float* w0, const float* w1, const float* w2, const float* w3,
    const float* w4, const float* w5, const float* w6, const float* w7,
    const float* w8, u16* __restrict__ out)
{
    const float* Ws[9] = {w0, w1, w2, w3, w4, w5, w6, w7, w8};
    const float* W = Ws[blockIdx.x];
    u16* o = out + (size_t)blockIdx.x * 16384;
    int tid = threadIdx.x;
#pragma unroll
    for (int it = 0; it < 8; ++it) {
        int slot = it * 256 + tid;       // 0..2047
        int f = slot >> 6, l = slot & 63;
        int kt = f >> 3, ct = f & 7;
        int row = ct * 16 + (l & 15);
        int kof = kt * 32 + (l >> 4) * 8;
        const float* wp = W + (size_t)row * HD + kof;
        float4 x = *(const float4*)wp;
        float4 y = *(const float4*)(wp + 4);
        uint4 pk;
        pk.x = pk2(x.x, x.y); pk.y = pk2(x.z, x.w);
        pk.z = pk2(y.x, y.y); pk.w = pk2(y.z, y.w);
        *(uint4*)(o + (size_t)slot * 8) = pk;
    }
}

// ---- combined histogram over both edge lists: dst var -> [0,NV), gene -> NV+ ----
__global__ __launch_bounds__(256) void hist2_kernel(const int* __restrict__ dst_gv,
                                                    const int* __restrict__ dst_vg,
                                                    int* __restrict__ deg) {
    int t = blockIdx.x * 256 + threadIdx.x;
    if (t < NE)            atomicAdd(&deg[dst_gv[t]], 1);
    else if (t < EALL)     atomicAdd(&deg[NV + dst_vg[t - NE]], 1);
}

// ---- scan stage 1: per-block (2048) exclusive scan + block sums ----
__global__ __launch_bounds__(256) void scan1_kernel(const int* __restrict__ deg,
                                                    int* __restrict__ excl,
                                                    int* __restrict__ bsum, int N) {
    __shared__ int lds[256];
    int tid = threadIdx.x;
    int base = blockIdx.x * 2048 + tid * 8;
    int v[8]; int s = 0;
#pragma unroll
    for (int i = 0; i < 8; ++i) { v[i] = (base + i < N) ? deg[base + i] : 0; s += v[i]; }
    lds[tid] = s;
    __syncthreads();
    for (int off = 1; off < 256; off <<= 1) {
        int x = (tid >= off) ? lds[tid - off] : 0;
        __syncthreads();
        lds[tid] += x;
        __syncthreads();
    }
    int run = lds[tid] - s;
#pragma unroll
    for (int i = 0; i < 8; ++i) {
        if (base + i < N) excl[base + i] = run;
        run += v[i];
    }
    if (tid == 255) bsum[blockIdx.x] = lds[255];
}

__global__ void scan2_kernel(int* __restrict__ bsum, int nb) {
    if (threadIdx.x == 0 && blockIdx.x == 0) {
        int run = 0;
        for (int i = 0; i < nb; ++i) { int t = bsum[i]; bsum[i] = run; run += t; }
    }
}

__global__ __launch_bounds__(256) void scan3_kernel(int* __restrict__ rs,
                                                    int* __restrict__ cur,
                                                    const int* __restrict__ bsum, int N) {
    int i = blockIdx.x * 256 + threadIdx.x;
    if (i < N) {
        int v = rs[i] + bsum[i >> 11];
        rs[i] = v;
        cur[i] = v;
    }
    if (i == 0) rs[N] = EALL;
}

// ---- combined edge scatter; esrc stored pre-offset into the combined table ----
__global__ __launch_bounds__(256) void escatter2_kernel(const int* __restrict__ src_gv,
                                                        const int* __restrict__ dst_gv,
                                                        const int* __restrict__ src_vg,
                                                        const int* __restrict__ dst_vg,
                                                        int* __restrict__ cur,
                                                        int* __restrict__ esrc) {
    int t = blockIdx.x * 256 + threadIdx.x;
    if (t < NE) {
        int p = atomicAdd(&cur[dst_gv[t]], 1);
        esrc[p] = src_gv[t];
    } else if (t < EALL) {
        int e = t - NE;
        int p = atomicAdd(&cur[NV + dst_vg[e]], 1);
        esrc[p] = NG + src_vg[e];
    }
}

// ---- fused aggregate + dual-segment MFMA SAGE linear ----
// Per 128-row block: (1) gather-mean its rows' neighbors into a swizzled
// 32 KB LDS bf16 tile; (2) dual-phase MFMA (phase0 A = LDS tile, phase1
// A = self rows from global); (3) coalesced epilogue via LDS (union'd).
// Swizzle: chunk (row, c) stored at row*256B + ((c ^ (row&15)))*16B.
// Fragment map (m89-verified): A row=lane&15, k=8*(lane>>4)+j; B col=lane&15;
// D col=lane&15, row=4*(lane>>4)+reg.
template <int RELU, int OBF16>
__global__ __launch_bounds__(256, 4) void fused_sage_kernel(
    const u16* __restrict__ Xb,     // combined [gene; var] bf16 table
    const int* __restrict__ rs,     // CSR row starts (var 0.., gene NV..)
    const int* __restrict__ esrc,   // edge sources (combined X row index)
    const u16* __restrict__ wf_v, const u16* __restrict__ wf_g,
    const float* __restrict__ b_v, const float* __restrict__ b_g,
    float* __restrict__ outf_v, float* __restrict__ outf_g,
    u16* __restrict__ outb_v, u16* __restrict__ outb_g,
    int nvb)
{
    __shared__ __align__(16) char ldsbuf[33792];   // atile 32768 | lds_t 33792 (union)
    u16* atile = (u16*)ldsbuf;

    const bool isVar = (int)blockIdx.x < nvb;
    const int bseg = isVar ? blockIdx.x : blockIdx.x - nvb;
    const int Nseg = isVar ? NV : NG;
    const int gseg = isVar ? 0 : NV;                      // CSR row-space offset
    const u16* Xseg = Xb + (size_t)(isVar ? NG : 0) * HD; // self rows
    const u16* wf = isVar ? wf_v : wf_g;
    const float* bias = isVar ? b_v : b_g;
    float* outf = isVar ? outf_v : outf_g;
    u16* outb = isVar ? outb_v : outb_g;

    const int tid = threadIdx.x;
    const int lane = tid & 63;
    const int wid = tid >> 6;
    const int m0 = bseg * 128 + wid * 32;
    const int lr = lane & 15, lg = lane >> 4;

    // ---- phase A: gather-mean 128 rows into swizzled LDS tile ----
    {
        const int c = tid & 15;
        for (int it = 0; it < 8; ++it) {
            int lrow = it * 16 + (tid >> 4);
            int srow = bseg * 128 + lrow;
            float s[8] = {0.f, 0.f, 0.f, 0.f, 0.f, 0.f, 0.f, 0.f};
            float rcv = 0.f;
            if (srow < Nseg) {
                int e0 = rs[gseg + srow], e1 = rs[gseg + srow + 1];
                int e = e0;
                for (; e + 2 <= e1; e += 2) {   // 2x unroll: two loads in flight
                    const u16* p0 = Xb + (size_t)esrc[e] * HD + c * 8;
                    const u16* p1 = Xb + (size_t)esrc[e + 1] * HD + c * 8;
                    uint4 u0 = *(const uint4*)p0;
                    uint4 u1 = *(const uint4*)p1;
                    u32 w0[4] = {u0.x, u0.y, u0.z, u0.w};
                    u32 w1[4] = {u1.x, u1.y, u1.z, u1.w};
#pragma unroll
                    for (int i = 0; i < 4; ++i) {
                        s[2 * i] += bflo(w0[i]) + bflo(w1[i]);
                        s[2 * i + 1] += bfhi(w0[i]) + bfhi(w1[i]);
                    }
                }
                if (e < e1) {
                    const u16* p = Xb + (size_t)esrc[e] * HD + c * 8;
                    uint4 u = *(const uint4*)p;
                    u32 w[4] = {u.x, u.y, u.z, u.w};
#pragma unroll
                    for (int i = 0; i < 4; ++i) { s[2 * i] += bflo(w[i]); s[2 * i + 1] += bfhi(w[i]); }
                }
                rcv = 1.f / fmaxf((float)(e1 - e0), 1.f);
            }
            uint4 pk;
            pk.x = pk2(s[0] * rcv, s[1] * rcv);
            pk.y = pk2(s[2] * rcv, s[3] * rcv);
            pk.z = pk2(s[4] * rcv, s[5] * rcv);
            pk.w = pk2(s[6] * rcv, s[7] * rcv);
            *(uint4*)(atile + lrow * 128 + ((c ^ (lrow & 15)) << 3)) = pk;
        }
    }
    __syncthreads();

    // ---- phase B: dual-phase MFMA ----
    f32x4 acc[2][8];
#pragma unroll
    for (int rt = 0; rt < 2; ++rt)
#pragma unroll
        for (int ct = 0; ct < 8; ++ct) acc[rt][ct] = (f32x4){0.f, 0.f, 0.f, 0.f};

    // phase 0: A = LDS agg tile (swizzled)
    {
        const u16* wp = wf;
        bf16x8 a[4][2];
#pragma unroll
        for (int kt = 0; kt < 4; ++kt)
#pragma unroll
            for (int rt = 0; rt < 2; ++rt) {
                int lrow = wid * 32 + rt * 16 + lr;
                int ck = (kt * 4 + lg) ^ (lrow & 15);
                a[kt][rt] = *(const bf16x8*)(atile + lrow * 128 + (ck << 3));
            }
#pragma unroll
        for (int kt = 0; kt < 4; ++kt)
#pragma unroll
            for (int ct = 0; ct < 8; ++ct) {
                bf16x8 w = *(const bf16x8*)(wp + (size_t)(((kt * 8 + ct) << 6) + lane) * 8);
#pragma unroll
                for (int rt = 0; rt < 2; ++rt)
                    acc[rt][ct] = __builtin_amdgcn_mfma_f32_16x16x32_bf16(
                        a[kt][rt], w, acc[rt][ct], 0, 0, 0);
            }
    }
    // phase 1: A = self rows from global
    {
        const u16* wp = wf + 16384;
        bf16x8 a[4][2];
#pragma unroll
        for (int kt = 0; kt < 4; ++kt)
#pragma unroll
            for (int rt = 0; rt < 2; ++rt) {
                int row = m0 + rt * 16 + lr; if (row > Nseg - 1) row = Nseg - 1;
                a[kt][rt] = *(const bf16x8*)(Xseg + (size_t)row * HD + kt * 32 + lg * 8);
            }
#pragma unroll
        for (int kt = 0; kt < 4; ++kt)
#pragma unroll
            for (int ct = 0; ct < 8; ++ct) {
                bf16x8 w = *(const bf16x8*)(wp + (size_t)(((kt * 8 + ct) << 6) + lane) * 8);
#pragma unroll
                for (int rt = 0; rt < 2; ++rt)
                    acc[rt][ct] = __builtin_amdgcn_mfma_f32_16x16x32_bf16(
                        a[kt][rt], w, acc[rt][ct], 0, 0, 0);
            }
    }

    float bv[8];
#pragma unroll
    for (int ct = 0; ct < 8; ++ct) bv[ct] = bias[ct * 16 + lr];

    // ---- phase C: epilogue via LDS (aliases atile -> barrier first) ----
    __syncthreads();
    float (*lds_t)[16][132] = (float (*)[16][132])ldsbuf;
#pragma unroll
    for (int rt = 0; rt < 2; ++rt) {
#pragma unroll
        for (int ct = 0; ct < 8; ++ct)
#pragma unroll
            for (int r = 0; r < 4; ++r) {
                float v = acc[rt][ct][r] + bv[ct];
                if (RELU) v = fmaxf(v, 0.f);
                lds_t[wid][lg * 4 + r][ct * 16 + lr] = v;
            }
        __syncthreads();
        if (OBF16 == 0) {
#pragma unroll
            for (int i = 0; i < 8; ++i) {
                int row16 = i * 2 + (lane >> 5);
                int colb = (lane & 31) * 4;
                f32x4 v = *(const f32x4*)&lds_t[wid][row16][colb];
                int grow = m0 + rt * 16 + row16;
                if (grow < Nseg) *(f32x4*)(outf + (size_t)grow * HD + colb) = v;
            }
        } else {
#pragma unroll
            for (int i = 0; i < 4; ++i) {
                int row16 = i * 4 + (lane >> 4);
                int colb = (lane & 15) * 8;
                f32x4 v0 = *(const f32x4*)&lds_t[wid][row16][colb];
                f32x4 v1 = *(const f32x4*)&lds_t[wid][row16][colb + 4];
                uint4 pk;
                pk.x = pk2(v0[0], v0[1]); pk.y = pk2(v0[2], v0[3]);
                pk.z = pk2(v1[0], v1[1]); pk.w = pk2(v1[2], v1[3]);
                int grow = m0 + rt * 16 + row16;
                if (grow < Nseg) *(uint4*)(outb + (size_t)grow * HD + colb) = pk;
            }
        }
        __syncthreads();
    }
}

// ---- fused adversarial head: adv = relu(g2 @ A1^T + b1) @ A2^T + b2 ----
__global__ __launch_bounds__(256, 4) void head_kernel(
    const float* __restrict__ g2,     // f32 [NG][128] (out_gene2)
    const u16* __restrict__ wfA1,     // A1 frag buf
    const float* __restrict__ b1,
    const float* __restrict__ A2,     // f32 [8][128]
    const float* __restrict__ b2,
    float* __restrict__ adv)          // f32 [NG][8]
{
    __shared__ __align__(16) u16 lds_h[4][16][136];
    const int tid = threadIdx.x;
    const int lane = tid & 63;
    const int wid = tid >> 6;
    const int m0 = blockIdx.x * 128 + wid * 32;
    const int lr = lane & 15, lg = lane >> 4;

    bf16x8 a2f[4];
#pragma unroll
    for (int kt = 0; kt < 4; ++kt) {
        union { u16 s[8]; bf16x8 v; } u;
        if (lr < 8) {
            const float* p = A2 + (size_t)lr * HD + kt * 32 + lg * 8;
            float4 x = *(const float4*)p;
            float4 y = *(const float4*)(p + 4);
            u.s[0] = f2bf(x.x); u.s[1] = f2bf(x.y); u.s[2] = f2bf(x.z); u.s[3] = f2bf(x.w);
            u.s[4] = f2bf(y.x); u.s[5] = f2bf(y.y); u.s[6] = f2bf(y.z); u.s[7] = f2bf(y.w);
        } else {
#pragma unroll
            for (int i = 0; i < 8; ++i) u.s[i] = 0;
        }
        a2f[kt] = u.v;
    }

    f32x4 acc[2][8];
#pragma unroll
    for (int rt = 0; rt < 2; ++rt)
#pragma unroll
        for (int ct = 0; ct < 8; ++ct) acc[rt][ct] = (f32x4){0.f, 0.f, 0.f, 0.f};

#pragma unroll
    for (int kt = 0; kt < 4; ++kt) {
        bf16x8 a[2];
#pragma unroll
        for (int rt = 0; rt < 2; ++rt) {
            int row = m0 + rt * 16 + lr; if (row > NG - 1) row = NG - 1;
            const float* p = g2 + (size_t)row * HD + kt * 32 + lg * 8;
            float4 x = *(const float4*)p;
            float4 y = *(const float4*)(p + 4);
            union { u16 s[8]; bf16x8 v; } u;
            u.s[0] = f2bf(x.x); u.s[1] = f2bf(x.y); u.s[2] = f2bf(x.z); u.s[3] = f2bf(x.w);
            u.s[4] = f2bf(y.x); u.s[5] = f2bf(y.y); u.s[6] = f2bf(y.z); u.s[7] = f2bf(y.w);
            a[rt] = u.v;
        }
#pragma unroll
        for (int ct = 0; ct < 8; ++ct) {
            bf16x8 w = *(const bf16x8*)(wfA1 + (size_t)(((kt * 8 + ct) << 6) + lane) * 8);
#pragma unroll
            for (int rt = 0; rt < 2; ++rt)
                acc[rt][ct] = __builtin_amdgcn_mfma_f32_16x16x32_bf16(
                    a[rt], w, acc[rt][ct], 0, 0, 0);
        }
    }

    float b1v[8];
#pragma unroll
    for (int ct = 0; ct < 8; ++ct) b1v[ct] = b1[ct * 16 + lr];
    float b2v = (lr < 8) ? b2[lr] : 0.f;

#pragma unroll
    for (int rt = 0; rt < 2; ++rt) {
#pragma unroll
        for (int ct = 0; ct < 8; ++ct)
#pragma unroll
            for (int r = 0; r < 4; ++r) {
                float v = fmaxf(acc[rt][ct][r] + b1v[ct], 0.f);
                lds_h[wid][lg * 4 + r][ct * 16 + lr] = f2bf(v);
            }
        __syncthreads();
        f32x4 av = (f32x4){0.f, 0.f, 0.f, 0.f};
#pragma unroll
        for (int kt = 0; kt < 4; ++kt) {
            bf16x8 h = *(const bf16x8*)&lds_h[wid][lr][kt * 32 + lg * 8];
            av = __builtin_amdgcn_mfma_f32_16x16x32_bf16(h, a2f[kt], av, 0, 0, 0);
        }
        if (lr < 8) {
#pragma unroll
            for (int r = 0; r < 4; ++r) {
                int grow = m0 + rt * 16 + lg * 4 + r;
                if (grow < NG) adv[(size_t)grow * 8 + lr] = av[r] + b2v;
            }
        }
        __syncthreads();
    }
}

extern "C" void kernel_launch(void* const* d_in, const int* in_sizes, int n_in,
                              void* d_out, int out_size, void* d_ws, size_t ws_size,
                              hipStream_t stream)
{
    const float* emb_gene = (const float*)d_in[0];
    const float* emb_var  = (const float*)d_in[1];
    const float* Wl1_gv = (const float*)d_in[2];
    const float* bl1_gv = (const float*)d_in[3];
    const float* Wr1_gv = (const float*)d_in[4];
    const float* Wl1_vg = (const float*)d_in[5];
    const float* bl1_vg = (const float*)d_in[6];
    const float* Wr1_vg = (const float*)d_in[7];
    const float* Wl2_gv = (const float*)d_in[8];
    const float* bl2_gv = (const float*)d_in[9];
    const float* Wr2_gv = (const float*)d_in[10];
    const float* Wl2_vg = (const float*)d_in[11];
    const float* bl2_vg = (const float*)d_in[12];
    const float* Wr2_vg = (const float*)d_in[13];
    const float* A1 = (const float*)d_in[14];
    const float* b1 = (const float*)d_in[15];
    const float* A2 = (const float*)d_in[16];
    const float* b2 = (const float*)d_in[17];
    const int* src_gv = (const int*)d_in[18];
    const int* dst_gv = (const int*)d_in[19];
    const int* src_vg = (const int*)d_in[20];
    const int* dst_vg = (const int*)d_in[21];

    // ws layout (bytes) — ws_size ≈ 627 MB (measured r5 poison fill):
    char* ws = (char*)d_ws;
    u16* embb  = (u16*)(ws);                  // bf16 [NALL][128] gene;var  76.8 MB
    u16* zb    = (u16*)(ws + 76800000);       // bf16 [NALL][128] gene;var  76.8 MB
    u16* wfrag = (u16*)(ws + 153600000);      // 9 x 32 KB fragment bufs
    int* rs    = (int*)(ws + 154000000);      // [NALL+1]
    int* esrc  = (int*)(ws + 155300000);      // [2E]
    int* deg   = (int*)(ws + 159300000);      // [NALL] transient
    int* cur   = (int*)(ws + 160500000);      // [NALL] transient
    int* bsum  = (int*)(ws + 161700000);      // [147]

    float* out       = (float*)d_out;
    float* out_gene2 = out;                          // [NG][128]
    float* out_var2  = out + (size_t)NG * HD;        // [NV][128]
    float* out_adv   = out + (size_t)(NG + NV) * HD; // [NG][8]

    const int NB = (NALL + 2047) / 2048;   // 147
    const int EB2 = (EALL + 255) / 256;    // 3907
    const int NVB = (NV + 127) / 128;      // 1563
    const int NGB = (NG + 127) / 128;      // 782
    const int CVB = (int)(((size_t)NALL * HD / 8 + 255) / 256);  // 18750

    // ---- prep: bf16 tables + W fragment bufs + CSR over combined graph ----
    hipMemsetAsync(deg, 0, (size_t)NALL * 4, stream);
    cvt_kernel<<<CVB, 256, 0, stream>>>(emb_gene, emb_var, embb);
    wcvt_kernel<<<9, 256, 0, stream>>>(Wl1_gv, Wr1_gv, Wl1_vg, Wr1_vg,
                                       Wl2_gv, Wr2_gv, Wl2_vg, Wr2_vg, A1, wfrag);
    hist2_kernel<<<EB2, 256, 0, stream>>>(dst_gv, dst_vg, deg);
    scan1_kernel<<<NB, 256, 0, stream>>>(deg, rs, bsum, NALL);
    scan2_kernel<<<1, 64, 0, stream>>>(bsum, NB);
    scan3_kernel<<<(NALL + 255) / 256, 256, 0, stream>>>(rs, cur, bsum, NALL);
    escatter2_kernel<<<EB2, 256, 0, stream>>>(src_gv, dst_gv, src_vg, dst_vg, cur, esrc);

    // ---- layer 1: fused gather-mean + MFMA dual-GEMM -> zb (bf16, relu) ----
    fused_sage_kernel<1, 1><<<NVB + NGB, 256, 0, stream>>>(embb, rs, esrc,
        wfrag + 0 * 16384, wfrag + 2 * 16384, bl1_gv, bl1_vg,
        nullptr, nullptr,
        zb + (size_t)NG * HD, zb,
        NVB);

    // ---- layer 2: fused gather-mean + MFMA dual-GEMM -> d_out (f32) ----
    fused_sage_kernel<0, 0><<<NVB + NGB, 256, 0, stream>>>(zb, rs, esrc,
        wfrag + 4 * 16384, wfrag + 6 * 16384, bl2_gv, bl2_vg,
        out_var2, out_gene2,
        nullptr, nullptr,
        NVB);

    // ---- fused adversarial head ----
    head_kernel<<<NGB, 256, 0, stream>>>(out_gene2, wfrag + 8 * 16384, b1, A2, b2, out_adv);
}